// Round 7
// baseline (8163.297 us; speedup 1.0000x reference)
//
#include <hip/hip_runtime.h>
#include <stdint.h>

// FPS: B=32, C=3, N=131072, M=2048, f32.
// Round 7: round-5 sync structure (2 barriers, sleep-poll, wave0-only exchange)
// + round-6 record format (coords folded into self-tagged u64 words).
// Lessons: R4 = no fences / few pollers; R6 = barriers beat spins (issue ports).

#define B_   32
#define N_   131072
#define M_   2048
#define WPB  8          // workgroups per batch
#define T_   1024       // threads per workgroup
#define PTS  16         // points per thread
#define ITERS (M_ - 1)
#define NPW  (N_ / WPB) // 16384 points per WG

typedef unsigned long long u64;

__global__ void __launch_bounds__(T_, 4)
fps_main(const float* __restrict__ x, float* __restrict__ y,
         u64* __restrict__ slots) {
    const int bid  = blockIdx.x;
    const int b    = bid & (B_ - 1);  // batch id; 8 WGs/batch
    const int wl   = bid >> 5;        // wg-local id 0..7
    const int tid  = threadIdx.x;
    const int lane = tid & 63;
    const int wave = tid >> 6;

    const float* __restrict__ xb = x + (size_t)b * 3u * N_;
    float* __restrict__ yb = y + (size_t)b * 3u * M_;
    const unsigned pbase = (unsigned)(wl * NPW + tid);

    // register-resident coords + running min-dists
    float X[PTS], Y[PTS], Z[PTS], D[PTS];
#pragma unroll
    for (int k = 0; k < PTS; ++k) {
        unsigned p = pbase + (unsigned)(k * T_);
        X[k] = xb[p];
        Y[k] = xb[N_ + p];
        Z[k] = xb[2 * N_ + p];
        D[k] = INFINITY;
    }

    float lx = xb[0], ly = xb[N_], lz = xb[2 * N_];
    if (wl == 0 && tid == 0) { yb[0] = lx; yb[M_] = ly; yb[2 * M_] = lz; }

    __shared__ u64   s_rec[16][4];  // per-wave winner: {key, x|tag, y|tag, z|tag}
    __shared__ float s_c[3];        // batch-winner coords

    // slots: [batch][parity][WPB][4] u64; each record = 32B (one coalesced store)

    for (int it = 0; it < ITERS; ++it) {
        const int par = it & 1;
        const unsigned ittag = (unsigned)it;   // 0..2046 in a 15-bit field

        // ---- update min-dists + thread-local best (strict > keeps lowest idx) ----
        float bv = -INFINITY; unsigned bi = 0u;
#pragma unroll
        for (int k = 0; k < PTS; ++k) {
            float dx = X[k] - lx;
            float dy = Y[k] - ly;
            float dz = Z[k] - lz;
            // match XLA rounding: ((dx*dx)+(dy*dy))+(dz*dz), no FMA contraction
            float d  = __fadd_rn(__fadd_rn(__fmul_rn(dx, dx), __fmul_rn(dy, dy)),
                                 __fmul_rn(dz, dz));
            float nd = fminf(D[k], d);
            D[k] = nd;
            bool t = nd > bv;
            bv = t ? nd : bv;
            bi = t ? (pbase + (unsigned)(k * T_)) : bi;
        }

        // key: [dist:32 | tag:15 | (0x1FFFF - idx):17]
        // tag bits equal across WGs within an iteration -> ordering is dist-major
        // then lowest-index (jnp.argmax first-match). Keys unique per point.
        u64 key = ((u64)__float_as_uint(bv) << 32)
                | ((u64)ittag << 17)
                | (u64)(0x1FFFFu - bi);

        // ---- wave butterfly max ----
        u64 wk = key;
#pragma unroll
        for (int off = 1; off < 64; off <<= 1) {
            u64 o = __shfl_xor(wk, off);
            wk = (o > wk) ? o : wk;
        }

        // unique winner lane deposits the wire-format record into LDS
        if (key == wk) {
            float bx = 0.f, by = 0.f, bz = 0.f;
#pragma unroll
            for (int k = 0; k < PTS; ++k)
                if (pbase + (unsigned)(k * T_) == bi) { bx = X[k]; by = Y[k]; bz = Z[k]; }
            s_rec[wave][0] = wk;
            s_rec[wave][1] = ((u64)__float_as_uint(bx) << 32) | (u64)ittag;
            s_rec[wave][2] = ((u64)__float_as_uint(by) << 32) | (u64)ittag;
            s_rec[wave][3] = ((u64)__float_as_uint(bz) << 32) | (u64)ittag;
        }
        __syncthreads();   // barrier #1: deposits visible to wave0 (parked waves don't issue)

        if (wave == 0) {
            // ---- combine 16 wave winners ----
            u64 k2 = (lane < 16) ? s_rec[lane][0] : 0ull;
            u64 m2 = k2;
#pragma unroll
            for (int off = 1; off < 16; off <<= 1) {
                u64 o = __shfl_xor(m2, off);
                m2 = (o > m2) ? o : m2;
            }
            u64 ball = __ballot(lane < 16 && k2 == m2);
            int wv = __ffsll((unsigned long long)ball) - 1;   // winning wave (keys unique)

            // ---- publish: lanes 0..3 emit the 32B record, one coalesced store ----
            u64* grec = slots + (size_t)(((b * 2 + par) * WPB + wl) * 4);
            if (lane < 4) {
                u64 word = s_rec[wv][lane];   // word0 == m2 by construction
                __hip_atomic_store(&grec[lane], word,
                                   __ATOMIC_RELAXED, __HIP_MEMORY_SCOPE_AGENT);
            }

            // ---- poll all 8 records (32 u64 = 4 lines); self-tagged words ----
            u64* gb = slots + (size_t)((b * 2 + par) * WPB * 4);
            const int w = lane & 3;
            u64 got = 0ull;
            for (int attempt = 0;; ++attempt) {
                if (lane < 32)
                    got = __hip_atomic_load(&gb[lane],
                                            __ATOMIC_RELAXED, __HIP_MEMORY_SCOPE_AGENT);
                bool ok = (lane >= 32) |
                          ((w == 0) ? (((unsigned)(got >> 17) & 0x7FFFu) == ittag)
                                    : (((unsigned)got & 0x7FFFu) == ittag));
                if (__all(ok)) break;
                __builtin_amdgcn_s_sleep(1);   // throttle only after a miss
            }

            // ---- batch winner: butterfly over key words + ballot + 3 shuffles ----
            u64 kk = (lane < 32 && w == 0) ? got : 0ull;
#pragma unroll
            for (int off = 1; off < 64; off <<= 1) {
                u64 o = __shfl_xor(kk, off);
                kk = (o > kk) ? o : kk;
            }
            u64 ball2 = __ballot(lane < 32 && w == 0 && got == kk);
            int winl = __ffsll((unsigned long long)ball2) - 1;  // lane holding winner key
            lx = __uint_as_float((unsigned)(__shfl(got, winl + 1) >> 32));
            ly = __uint_as_float((unsigned)(__shfl(got, winl + 2) >> 32));
            lz = __uint_as_float((unsigned)(__shfl(got, winl + 3) >> 32));
            if (lane == 0) { s_c[0] = lx; s_c[1] = ly; s_c[2] = lz; }
        }
        __syncthreads();   // barrier #2: winner coords visible to all waves

        lx = s_c[0]; ly = s_c[1]; lz = s_c[2];
        if (wl == 0 && wave == 1 && lane == 0) {   // output store off the critical wave
            yb[it + 1]          = lx;
            yb[M_ + it + 1]     = ly;
            yb[2 * M_ + it + 1] = lz;
        }
    }
}

extern "C" void kernel_launch(void* const* d_in, const int* in_sizes, int n_in,
                              void* d_out, int out_size, void* d_ws, size_t ws_size,
                              hipStream_t stream) {
    const float* x = (const float*)d_in[0];
    float* y = (float*)d_out;
    u64* slots = (u64*)d_ws;   // 32 batches * 2 parity * 8 WG * 4 u64 = 16 KiB
    // No init kernel: every word is self-tagged; 0xAA poison tags (0x5555/0x2AAA)
    // never match a wanted tag in [0, 2046]; harness re-poisons d_ws each launch.
    fps_main<<<B_ * WPB, T_, 0, stream>>>(x, y, slots);
}

// Round 8
// 7471.475 us; speedup vs baseline: 1.0926x; 1.0926x over previous
//
#include <hip/hip_runtime.h>
#include <stdint.h>

// FPS: B=32, C=3, N=131072, M=2048, f32.
// Round 8: two-batch interleave. Each WG serves batches (pp, pp+16); the
// exchange latency of one batch hides under the other batch's update.
// Per-batch protocol = proven R5: one self-tagged u64 key per WG, wave0-only
// poll of one small slot set, relaxed atomics, no fences, barriers not spins,
// winner coords re-fetched from immutable x.

#define B_    32
#define N_    131072
#define M_    2048
#define PAIRS 16        // batch pairs; pair pp = batches (pp, pp+16)
#define WPB   16        // WGs per batch
#define T_    1024      // threads per WG
#define PTS   8         // points per thread per batch
#define ITERS (M_ - 1)
#define NPW   (N_ / WPB) // 8192 points per WG per batch

typedef unsigned long long u64;

__device__ __forceinline__ u64 wave_max64(u64 v) {
#pragma unroll
    for (int off = 1; off < 64; off <<= 1) {
        u64 o = __shfl_xor(v, off);
        v = (o > v) ? o : v;
    }
    return v;
}

__global__ void __launch_bounds__(T_, 4)
fps_main(const float* __restrict__ x, float* __restrict__ y,
         u64* __restrict__ slots) {
    const int wg   = blockIdx.x;
    const int pp   = wg & (PAIRS - 1);  // pair id; WGs of a pair share wg%16 -> same XCD under round-robin (perf only)
    const int wl   = wg >> 4;           // 0..15 wg-local id within the pair
    const int bA   = pp;
    const int bB   = pp + PAIRS;
    const int tid  = threadIdx.x;
    const int lane = tid & 63;
    const int wave = tid >> 6;

    const float* __restrict__ xA = x + (size_t)bA * 3u * N_;
    const float* __restrict__ xB = x + (size_t)bB * 3u * N_;
    float* __restrict__ yA = y + (size_t)bA * 3u * M_;
    float* __restrict__ yB = y + (size_t)bB * 3u * M_;
    const unsigned pbase = (unsigned)(wl * NPW + tid);

    // register-resident state: 2 batches x 8 pts x {x,y,z,d} = 64 VGPRs
    float XA[PTS], YA[PTS], ZA[PTS], DA[PTS];
    float XB[PTS], YB[PTS], ZB[PTS], DB[PTS];
#pragma unroll
    for (int k = 0; k < PTS; ++k) {
        unsigned p = pbase + (unsigned)(k * T_);
        XA[k] = xA[p]; YA[k] = xA[N_ + p]; ZA[k] = xA[2*N_ + p]; DA[k] = INFINITY;
        XB[k] = xB[p]; YB[k] = xB[N_ + p]; ZB[k] = xB[2*N_ + p]; DB[k] = INFINITY;
    }

    float lxA = xA[0], lyA = xA[N_], lzA = xA[2*N_];
    float lxB = xB[0], lyB = xB[N_], lzB = xB[2*N_];
    if (wl == 0 && tid == 0) {
        yA[0] = lxA; yA[M_] = lyA; yA[2*M_] = lzA;
        yB[0] = lxB; yB[M_] = lyB; yB[2*M_] = lzB;
    }

    __shared__ u64   s_keyA[16], s_keyB[16];
    __shared__ float s_cA[3], s_cB[3];

    // slots: [batch][parity][WPB] u64; per-batch set = 128B = 2 lines.
    // Self-tagged keys: [dist:32 | tag:15 | (0x1FFFF - idx):17]. 0xAA poison
    // tag = 0x5555 > 2046, stale tags differ -> no init kernel needed.

    for (int it = 0; it < ITERS; ++it) {
        const int par = it & 1;
        const unsigned ittag = (unsigned)it;

        // ---------- batch A: update + wave reduce + deposit ----------
        {
            float bv = -INFINITY; unsigned bi = 0u;
#pragma unroll
            for (int k = 0; k < PTS; ++k) {
                float dx = XA[k]-lxA, dy = YA[k]-lyA, dz = ZA[k]-lzA;
                // match XLA rounding: ((dx*dx)+(dy*dy))+(dz*dz), no FMA
                float d  = __fadd_rn(__fadd_rn(__fmul_rn(dx,dx), __fmul_rn(dy,dy)),
                                     __fmul_rn(dz,dz));
                float nd = fminf(DA[k], d);
                DA[k] = nd;
                bool t = nd > bv;
                bv = t ? nd : bv;
                bi = t ? (pbase + (unsigned)(k * T_)) : bi;
            }
            u64 key = ((u64)__float_as_uint(bv) << 32)
                    | ((u64)ittag << 17) | (u64)(0x1FFFFu - bi);
            key = wave_max64(key);
            if (lane == 0) s_keyA[wave] = key;
        }
        __syncthreads();   // barrier 1: A deposits visible

        // wave0 publishes A while waves 1..15 proceed into B's update
        if (wave == 0) {
            u64 k2 = (lane < 16) ? s_keyA[lane] : 0ull;
#pragma unroll
            for (int off = 1; off < 16; off <<= 1) {
                u64 o = __shfl_xor(k2, off);
                k2 = (o > k2) ? o : k2;
            }
            if (lane == 0)
                __hip_atomic_store(slots + (size_t)((bA*2+par)*WPB + wl), k2,
                                   __ATOMIC_RELAXED, __HIP_MEMORY_SCOPE_AGENT);
        }

        // ---------- batch B: update + wave reduce + deposit ----------
        {
            float bv = -INFINITY; unsigned bi = 0u;
#pragma unroll
            for (int k = 0; k < PTS; ++k) {
                float dx = XB[k]-lxB, dy = YB[k]-lyB, dz = ZB[k]-lzB;
                float d  = __fadd_rn(__fadd_rn(__fmul_rn(dx,dx), __fmul_rn(dy,dy)),
                                     __fmul_rn(dz,dz));
                float nd = fminf(DB[k], d);
                DB[k] = nd;
                bool t = nd > bv;
                bv = t ? nd : bv;
                bi = t ? (pbase + (unsigned)(k * T_)) : bi;
            }
            u64 key = ((u64)__float_as_uint(bv) << 32)
                    | ((u64)ittag << 17) | (u64)(0x1FFFFu - bi);
            key = wave_max64(key);
            if (lane == 0) s_keyB[wave] = key;
        }
        __syncthreads();   // barrier 2: B deposits visible

        if (wave == 0) {
            // combine + publish B
            u64 k2 = (lane < 16) ? s_keyB[lane] : 0ull;
#pragma unroll
            for (int off = 1; off < 16; off <<= 1) {
                u64 o = __shfl_xor(k2, off);
                k2 = (o > k2) ? o : k2;
            }
            if (lane == 0)
                __hip_atomic_store(slots + (size_t)((bB*2+par)*WPB + wl), k2,
                                   __ATOMIC_RELAXED, __HIP_MEMORY_SCOPE_AGENT);

            // ---- poll A (published one B-update ago; mostly landed) ----
            u64* gbA = slots + (size_t)((bA*2+par)*WPB);
            u64 gotA = 0ull;
            for (;;) {
                if (lane < WPB)
                    gotA = __hip_atomic_load(gbA + lane,
                                             __ATOMIC_RELAXED, __HIP_MEMORY_SCOPE_AGENT);
                bool ok = (lane >= WPB) | (((unsigned)(gotA >> 17) & 0x7FFFu) == ittag);
                if (__all(ok)) break;
                __builtin_amdgcn_s_sleep(1);
            }
            u64 kA = (lane < WPB) ? gotA : 0ull;
#pragma unroll
            for (int off = 1; off < 16; off <<= 1) {
                u64 o = __shfl_xor(kA, off);
                kA = (o > kA) ? o : kA;
            }
            unsigned widxA = 0x1FFFFu - (unsigned)(kA & 0x1FFFFu);
            if (lane < 3) s_cA[lane] = xA[(size_t)lane * N_ + widxA];

            // ---- poll B ----
            u64* gbB = slots + (size_t)((bB*2+par)*WPB);
            u64 gotB = 0ull;
            for (;;) {
                if (lane < WPB)
                    gotB = __hip_atomic_load(gbB + lane,
                                             __ATOMIC_RELAXED, __HIP_MEMORY_SCOPE_AGENT);
                bool ok = (lane >= WPB) | (((unsigned)(gotB >> 17) & 0x7FFFu) == ittag);
                if (__all(ok)) break;
                __builtin_amdgcn_s_sleep(1);
            }
            u64 kB = (lane < WPB) ? gotB : 0ull;
#pragma unroll
            for (int off = 1; off < 16; off <<= 1) {
                u64 o = __shfl_xor(kB, off);
                kB = (o > kB) ? o : kB;
            }
            unsigned widxB = 0x1FFFFu - (unsigned)(kB & 0x1FFFFu);
            if (lane < 3) s_cB[lane] = xB[(size_t)lane * N_ + widxB];
        }
        __syncthreads();   // barrier 3: winners visible

        lxA = s_cA[0]; lyA = s_cA[1]; lzA = s_cA[2];
        lxB = s_cB[0]; lyB = s_cB[1]; lzB = s_cB[2];
        if (wl == 0 && lane == 0) {   // output stores off the critical wave
            if (wave == 1) { yA[it+1] = lxA; yA[M_+it+1] = lyA; yA[2*M_+it+1] = lzA; }
            if (wave == 2) { yB[it+1] = lxB; yB[M_+it+1] = lyB; yB[2*M_+it+1] = lzB; }
        }
    }
}

extern "C" void kernel_launch(void* const* d_in, const int* in_sizes, int n_in,
                              void* d_out, int out_size, void* d_ws, size_t ws_size,
                              hipStream_t stream) {
    const float* x = (const float*)d_in[0];
    float* y = (float*)d_out;
    u64* slots = (u64*)d_ws;   // 32 batches * 2 parity * 16 WG * 8B = 8 KiB
    fps_main<<<B_ * WPB / 2, T_, 0, stream>>>(x, y, slots);
}

// Round 9
// 7127.507 us; speedup vs baseline: 1.1453x; 1.0483x over previous
//
#include <hip/hip_runtime.h>
#include <stdint.h>

// FPS: B=32, C=3, N=131072, M=2048, f32.
// Round 9: R5 structure (best measured: 2 barriers, wave0-only engine,
// 1-line/8-key detect set, relaxed atomics, no fences) + coords shipped on
// SIDE lines co-loaded during the poll (validated post-detect, rare reload).
// Removes the serial post-detect coord fetch (~0.25us + variance) from the
// 2.73us/step chain without touching the proven detect set.

#define B_   32
#define N_   131072
#define M_   2048
#define WPB  8          // workgroups per batch
#define T_   1024       // threads per workgroup
#define PTS  16         // points per thread
#define ITERS (M_ - 1)
#define NPW  (N_ / WPB) // 16384 points per WG

typedef unsigned long long u64;

// ws layout (u64 units):
//   [0, 512)          key slots: [batch][parity][WPB]           (64B/batch-par = 1 line)
//   [512, 512+2048)   coord recs: [batch][parity][WPB][4]       {x|tag, y|tag, z|tag, pad}

__global__ void __launch_bounds__(T_, 4)
fps_main(const float* __restrict__ x, float* __restrict__ y,
         u64* __restrict__ ws) {
    const int bid  = blockIdx.x;
    const int b    = bid & (B_ - 1);
    const int wl   = bid >> 5;        // 0..7 wg-local id within batch
    const int tid  = threadIdx.x;
    const int lane = tid & 63;
    const int wave = tid >> 6;

    const float* __restrict__ xb = x + (size_t)b * 3u * N_;
    float* __restrict__ yb = y + (size_t)b * 3u * M_;
    const unsigned pbase = (unsigned)(wl * NPW + tid);

    // register-resident coords + running min-dists
    float X[PTS], Y[PTS], Z[PTS], D[PTS];
#pragma unroll
    for (int k = 0; k < PTS; ++k) {
        unsigned p = pbase + (unsigned)(k * T_);
        X[k] = xb[p];
        Y[k] = xb[N_ + p];
        Z[k] = xb[2 * N_ + p];
        D[k] = INFINITY;
    }

    float lx = xb[0], ly = xb[N_], lz = xb[2 * N_];
    if (wl == 0 && tid == 0) { yb[0] = lx; yb[M_] = ly; yb[2 * M_] = lz; }

    __shared__ u64 s_key[16];
    __shared__ u64 s_cand[16][5];   // [0..2] used; stride 5 u64 de-conflicts banks
    __shared__ float s_c[3];

    for (int it = 0; it < ITERS; ++it) {
        const int par = it & 1;
        const unsigned ittag = (unsigned)it;   // 0..2046; poison 0xAAAAAAAA never matches

        // ---- update min-dists + thread-local best (strict > keeps lowest idx) ----
        float bv = -INFINITY; unsigned bi = 0u;
#pragma unroll
        for (int k = 0; k < PTS; ++k) {
            float dx = X[k] - lx;
            float dy = Y[k] - ly;
            float dz = Z[k] - lz;
            // match XLA rounding: ((dx*dx)+(dy*dy))+(dz*dz), no FMA contraction
            float d  = __fadd_rn(__fadd_rn(__fmul_rn(dx, dx), __fmul_rn(dy, dy)),
                                 __fmul_rn(dz, dz));
            float nd = fminf(D[k], d);
            D[k] = nd;
            bool t = nd > bv;
            bv = t ? nd : bv;
            bi = t ? (pbase + (unsigned)(k * T_)) : bi;
        }

        // key: [dist:32 | tag:15 | (0x1FFFF - idx):17]  (unique; argmax-first ties)
        u64 key = ((u64)__float_as_uint(bv) << 32)
                | ((u64)ittag << 17)
                | (u64)(0x1FFFFu - bi);

        // ---- wave butterfly max ----
        u64 wk = key;
#pragma unroll
        for (int off = 1; off < 64; off <<= 1) {
            u64 o = __shfl_xor(wk, off);
            wk = (o > wk) ? o : wk;
        }

        // unique owner lane deposits key + candidate coords (self-tagged words)
        if (key == wk) {
            float bx = 0.f, by = 0.f, bz = 0.f;
#pragma unroll
            for (int k = 0; k < PTS; ++k)
                if (pbase + (unsigned)(k * T_) == bi) { bx = X[k]; by = Y[k]; bz = Z[k]; }
            s_key[wave] = wk;
            s_cand[wave][0] = ((u64)__float_as_uint(bx) << 32) | (u64)ittag;
            s_cand[wave][1] = ((u64)__float_as_uint(by) << 32) | (u64)ittag;
            s_cand[wave][2] = ((u64)__float_as_uint(bz) << 32) | (u64)ittag;
        }
        __syncthreads();   // barrier 1: deposits visible to wave0

        if (wave == 0) {
            // ---- combine 16 wave winners ----
            u64 k2 = (lane < 16) ? s_key[lane] : 0ull;
            u64 m2 = k2;
#pragma unroll
            for (int off = 1; off < 16; off <<= 1) {
                u64 o = __shfl_xor(m2, off);
                m2 = (o > m2) ? o : m2;
            }
            u64 ball = __ballot(lane < 16 && k2 == m2);
            int wvWave = __ffsll(ball) - 1;     // winning wave within WG (keys unique)

            u64* keybase = ws + (size_t)(b * 2 + par) * WPB;
            u64* cbase   = ws + 512 + (size_t)(b * 2 + par) * WPB * 4;

            // ---- publish: coords first (3 lanes), then key (lane 0) ----
            if (lane < 3)
                __hip_atomic_store(cbase + wl * 4 + lane, s_cand[wvWave][lane],
                                   __ATOMIC_RELAXED, __HIP_MEMORY_SCOPE_AGENT);
            if (lane == 0)
                __hip_atomic_store(keybase + wl, m2,
                                   __ATOMIC_RELAXED, __HIP_MEMORY_SCOPE_AGENT);

            // ---- poll keys (1-line detect set) + co-load coord recs ----
            const int r = (lane - 32) >> 2, c = (lane - 32) & 3;
            u64 gk = 0ull, gc = 0ull;
            for (;;) {
                if (lane < WPB)
                    gk = __hip_atomic_load(keybase + lane,
                                           __ATOMIC_RELAXED, __HIP_MEMORY_SCOPE_AGENT);
                if (lane >= 32)
                    gc = __hip_atomic_load(cbase + (lane - 32),
                                           __ATOMIC_RELAXED, __HIP_MEMORY_SCOPE_AGENT);
                bool ok = (lane >= WPB) | (((unsigned)(gk >> 17) & 0x7FFFu) == ittag);
                if (__all(ok)) break;
                __builtin_amdgcn_s_sleep(1);
            }

            // ---- batch winner among the 8 keys ----
            u64 kk = (lane < WPB) ? gk : 0ull;
#pragma unroll
            for (int off = 1; off < 8; off <<= 1) {
                u64 o = __shfl_xor(kk, off);
                kk = (o > kk) ? o : kk;
            }
            u64 ball2 = __ballot(lane < WPB && gk == kk);
            int wvWG = __ffsll(ball2) - 1;      // winning WG slot (wave-uniform)

            // ---- winner coords: usually already in gc; validate, rare reload ----
            bool isw = (lane >= 32) && (r == wvWG) && (c < 3);
            bool bad = isw && ((unsigned)gc != ittag);
            if (__any(bad)) {
                if (lane < 3) {
                    u64 w;
                    do {
                        w = __hip_atomic_load(cbase + wvWG * 4 + lane,
                                              __ATOMIC_RELAXED, __HIP_MEMORY_SCOPE_AGENT);
                    } while ((unsigned)w != ittag);
                    s_c[lane] = __uint_as_float((unsigned)(w >> 32));
                }
            } else if (isw) {
                s_c[c] = __uint_as_float((unsigned)(gc >> 32));
            }
        }
        __syncthreads();   // barrier 2: winner coords visible to all waves

        lx = s_c[0]; ly = s_c[1]; lz = s_c[2];
        if (wl == 0 && wave == 1 && lane == 0) {   // output store off the engine wave
            yb[it + 1]          = lx;
            yb[M_ + it + 1]     = ly;
            yb[2 * M_ + it + 1] = lz;
        }
    }
}

extern "C" void kernel_launch(void* const* d_in, const int* in_sizes, int n_in,
                              void* d_out, int out_size, void* d_ws, size_t ws_size,
                              hipStream_t stream) {
    const float* x = (const float*)d_in[0];
    float* y = (float*)d_out;
    u64* ws = (u64*)d_ws;   // 4 KiB keys + 16 KiB coord recs = 20 KiB
    // No init kernel: every word is self-tagged; 0xAA poison never matches a
    // wanted tag in [0, 2046]; stale tags from prior replay differ by >=2.
    fps_main<<<B_ * WPB, T_, 0, stream>>>(x, y, ws);
}

// Round 10
// 6460.064 us; speedup vs baseline: 1.2637x; 1.1033x over previous
//
#include <hip/hip_runtime.h>
#include <stdint.h>

// FPS: B=32, C=3, N=131072, M=2048, f32.
// Round 10: exact R5 structure (best measured: 5578us) with ONLY the exchange
// load-path changed:
//   - publisher: volatile store (seeds local L2, same-XCD fast path) then
//     agent atomic store (LLC, cross-XCD correctness)
//   - poll: sc0 loads (L1-bypass, L2-capable) 3 of 4 attempts; agent atomic
//     load every 4th attempt as placement-independent fallback
//   - parity slot groups padded to 128B (no cross-parity false sharing)
// Self-tagged words make any stale/garbage read harmless (tag mismatch).

#define B_   32
#define N_   131072
#define M_   2048
#define WPB  8          // workgroups per batch
#define T_   1024       // threads per workgroup
#define PTS  16         // points per thread
#define ITERS (M_ - 1)
#define NPW  (N_ / WPB) // 16384 points per WG
#define PSTRIDE 16      // u64 per [batch][parity] slot group (128B line isolation)

typedef unsigned long long u64;

__global__ void __launch_bounds__(T_, 4)
fps_main(const float* __restrict__ x, float* __restrict__ y,
         u64* __restrict__ slots) {
    const int bid  = blockIdx.x;
    const int b    = bid & (B_ - 1);  // batch id; all 8 WGs of a batch share bid%8
                                      // -> same XCD under round-robin dispatch (perf heuristic only)
    const int wl   = bid >> 5;        // wg-local id 0..7
    const int tid  = threadIdx.x;
    const int lane = tid & 63;
    const int wave = tid >> 6;

    const float* __restrict__ xb = x + (size_t)b * 3u * N_;
    float* __restrict__ yb = y + (size_t)b * 3u * M_;
    const unsigned pbase = (unsigned)(wl * NPW + tid);

    // register-resident coords + running min-dists
    float X[PTS], Y[PTS], Z[PTS], D[PTS];
#pragma unroll
    for (int k = 0; k < PTS; ++k) {
        unsigned p = pbase + (unsigned)(k * T_);
        X[k] = xb[p];
        Y[k] = xb[N_ + p];
        Z[k] = xb[2 * N_ + p];
        D[k] = INFINITY;
    }

    float lx = xb[0], ly = xb[N_], lz = xb[2 * N_];
    if (wl == 0 && tid == 0) { yb[0] = lx; yb[M_] = ly; yb[2 * M_] = lz; }

    __shared__ u64   s_key[16];
    __shared__ float s_c[3];     // winner coords

    for (int it = 0; it < ITERS; ++it) {
        const int par = it & 1;
        const unsigned ittag = (unsigned)it;   // 0..2046; 0xAA poison never matches

        // ---- update min-dists + thread-local best (strict > keeps lowest idx) ----
        float bv = -INFINITY; unsigned bi = 0u;
#pragma unroll
        for (int k = 0; k < PTS; ++k) {
            float dx = X[k] - lx;
            float dy = Y[k] - ly;
            float dz = Z[k] - lz;
            // match XLA rounding: ((dx*dx)+(dy*dy))+(dz*dz), no FMA contraction
            float d  = __fadd_rn(__fadd_rn(__fmul_rn(dx, dx), __fmul_rn(dy, dy)),
                                 __fmul_rn(dz, dz));
            float nd = fminf(D[k], d);
            D[k] = nd;
            bool t = nd > bv;
            bv = t ? nd : bv;
            bi = t ? (pbase + (unsigned)(k * T_)) : bi;
        }

        // key: [dist:32 | tag:15 | (0x1FFFF - idx):17]
        // tag bits equal across WGs within an iteration -> ordering is dist-major
        // then lowest-index (jnp.argmax first-match). Keys unique per point.
        u64 key = ((u64)__float_as_uint(bv) << 32)
                | ((u64)ittag << 17)
                | (u64)(0x1FFFFu - bi);

        // ---- wave butterfly max ----
#pragma unroll
        for (int off = 1; off < 64; off <<= 1) {
            u64 o = __shfl_xor(key, off);
            key = (o > key) ? o : key;
        }
        if (lane == 0) s_key[wave] = key;
        __syncthreads();   // barrier 1: wave winners visible to wave0

        // ---- wave 0: combine, publish, poll, fetch coords ----
        if (wave == 0) {
            u64 k2 = (lane < 16) ? s_key[lane] : 0ull;
#pragma unroll
            for (int off = 1; off < 16; off <<= 1) {
                u64 o = __shfl_xor(k2, off);
                k2 = (o > k2) ? o : k2;
            }

            u64* base = slots + (size_t)(b * 2 + par) * PSTRIDE;
            if (lane == 0) {
                u64* sp = base + wl;
                *(volatile u64*)sp = k2;            // seed local L2 (same-XCD fast path)
                asm volatile("" ::: "memory");      // keep store order
                __hip_atomic_store(sp, k2,          // LLC: cross-XCD correctness
                                   __ATOMIC_RELAXED, __HIP_MEMORY_SCOPE_AGENT);
            }

            // poll the 8 slots (one 64B region): sc0 fast loads + atomic fallback
            unsigned tries = 0;
            u64 got = 0ull;
            for (;;) {
                if (lane < WPB) {
                    if ((tries & 3u) == 3u) {
                        got = __hip_atomic_load(base + lane,
                                                __ATOMIC_RELAXED, __HIP_MEMORY_SCOPE_AGENT);
                    } else {
                        const u64* p = base + lane;
                        u64 v;
                        asm volatile("global_load_dwordx2 %0, %1, off sc0\n\t"
                                     "s_waitcnt vmcnt(0)"
                                     : "=v"(v) : "v"(p) : "memory");
                        got = v;
                    }
                }
                bool ok = (lane >= WPB) |
                          (((unsigned)(got >> 17) & 0x7FFFu) == ittag);
                if (__all(ok)) break;
                ++tries;
            }

            // batch winner = max of the 8 slot keys
            u64 w = (lane < WPB) ? got : 0ull;
#pragma unroll
            for (int off = 1; off < 8; off <<= 1) {
                u64 o = __shfl_xor(w, off);
                w = (o > w) ? o : w;
            }
            unsigned widx = 0x1FFFFu - (unsigned)(w & 0x1FFFFu);
            // coords from the immutable input: no ordering needed
            if (lane < 3) s_c[lane] = xb[(size_t)lane * N_ + widx];
        }
        __syncthreads();   // barrier 2: winner coords visible to all waves

        lx = s_c[0]; ly = s_c[1]; lz = s_c[2];
        if (wl == 0 && tid == 0) {
            yb[it + 1]          = lx;
            yb[M_ + it + 1]     = ly;
            yb[2 * M_ + it + 1] = lz;
        }
    }
}

extern "C" void kernel_launch(void* const* d_in, const int* in_sizes, int n_in,
                              void* d_out, int out_size, void* d_ws, size_t ws_size,
                              hipStream_t stream) {
    const float* x = (const float*)d_in[0];
    float* y = (float*)d_out;
    u64* slots = (u64*)d_ws;   // 32 batches * 2 parity * 16 u64 = 8 KiB
    // No init kernel: keys are self-tagged; 0xAA poison (tag 0x5555) never
    // matches a wanted tag in [0, 2046]; harness re-poisons d_ws each launch.
    fps_main<<<B_ * WPB, T_, 0, stream>>>(x, y, slots);
}